// Round 6
// baseline (29.720 us; speedup 1.0000x reference)
//
#include <hip/hip_runtime.h>

// PhraseModel: two VQ argmins (z, z_pre vs codebook) + phrase gather + sum.
// Round 6: bf16 hi/lo split MFMA ranking (3 exact products, err ~2e-4 rms)
// with tau-gated exact-f32 refinement (only rows with top2 gap < 0.0625).
// M=32 rows/block, 8 waves (4 code-waves x 2 K-halves), wave = 2 row-frags
// x 2 code-frags (reads/MFMA = 0.67). z staged once in LDS; cb chunks
// double-buffered via global_load_lds with depth-1 prefetch.

#define BHALF 4096
#define D 510
#define K_CODES 128
#define CHB 32768                 // cb image chunk: 16KB hi + 16KB lo
#define NCHUNK 8
#define TAU 0.0625f
#define WS_NEED (512 + NCHUNK * CHB)

using f32x4  = __attribute__((ext_vector_type(4))) float;
using bf16x8 = __attribute__((ext_vector_type(8))) short;

__device__ __forceinline__ unsigned short f2bf(float f) {
    union { float f; unsigned int u; } v; v.f = f;
    return (unsigned short)((v.u + 0x7FFFu + ((v.u >> 16) & 1u)) >> 16); // RTNE
}
__device__ __forceinline__ float bf2f(unsigned short h) {
    union { unsigned int u; float f; } v; v.u = ((unsigned int)h) << 16;
    return v.f;
}
__device__ __forceinline__ bool lexlt(float va, int ia, float vb, int ib) {
    return va < vb || (va == vb && ia < ib);
}
#define MFMA16 __builtin_amdgcn_mfma_f32_16x16x32_bf16

// ---- prep: cnorm + pre-swizzled bf16 hi/lo codebook image (8 chunks) ----
__global__ void prep_kernel(const float* __restrict__ cb,
                            float* __restrict__ cnorm,
                            char* __restrict__ img) {
    const int code = blockIdx.x;      // 0..127
    const int l = threadIdx.x;        // 0..63
    const int swz = (code & 7) << 4;
    float s = 0.f;
    #pragma unroll
    for (int i = 0; i < 8; ++i) {
        const int k = l + 64 * i;     // 0..511, pad 510/511 -> 0
        const float v = (k < D) ? cb[(size_t)code * D + k] : 0.f;
        s = fmaf(v, v, s);
        const unsigned short hi = f2bf(v);
        const unsigned short lo = f2bf(v - bf2f(hi));
        char* base = img + (size_t)(k >> 6) * CHB + code * 128;
        const int off = ((k & 63) * 2) ^ swz;   // XOR bits 4-6, stays in row
        *(unsigned short*)(base + off) = hi;
        *(unsigned short*)(base + 16384 + off) = lo;
    }
    #pragma unroll
    for (int m = 1; m < 64; m <<= 1) s += __shfl_xor(s, m, 64);
    if (l == 0) cnorm[code] = s;
}

// ---- main: MFMA distances + top2 + tau-gated refine + gather ----
// 256 blocks x 512 thr (8 waves: wn=wu&3 code-group, kh=wu>>2 K-half).
// Block rows: M-rows 0..15 = z[r0..r0+16], 16..31 = zp[r0..r0+16].
// Wave frags: rows {l15, 16+l15} (2 rf), codes {wn*32+l15, +16} (2 cf).
// LDS: cbbuf0 32K | cbbuf1 32K | z_hi 32K | z_lo 32K = 128KB.
__launch_bounds__(512, 1)
__global__ void main_kernel(const float* __restrict__ z,
                            const float* __restrict__ zp,
                            const float* __restrict__ cb,
                            const float* __restrict__ ph,
                            const int* __restrict__ pos,
                            const float* __restrict__ cnorm,
                            const char* __restrict__ img,
                            float* __restrict__ out) {
    __shared__ __align__(1024) char lds[131072];

    const int tid  = threadIdx.x;
    const int lane = tid & 63;
    const int wu   = __builtin_amdgcn_readfirstlane(tid >> 6); // 0..7
    const int wn   = wu & 3;
    const int kh   = wu >> 2;
    const int l15  = lane & 15;
    const int kg16 = (lane >> 4) * 16;
    const int r0   = blockIdx.x * 16;

    // ---- stage z once: 32 rows x 512 cols, hi/lo, XOR-swizzled ----
    #pragma unroll
    for (int i = 0; i < 8; ++i) {
        const int u = tid + 512 * i;          // float4-unit 0..4095
        const int row = u >> 7;
        const int col = (u & 127) * 4;        // 0..508
        const float* src = (row < 16) ? z + (size_t)(r0 + row) * D
                                      : zp + (size_t)(r0 + row - 16) * D;
        const float2 va = *(const float2*)(src + col);           // cols<=509 ok
        const float2 vb = (col + 2 < D) ? *(const float2*)(src + col + 2)
                                        : make_float2(0.f, 0.f);
        const unsigned short h0 = f2bf(va.x), h1 = f2bf(va.y),
                             h2 = f2bf(vb.x), h3 = f2bf(vb.y);
        const unsigned short g0 = f2bf(va.x - bf2f(h0)), g1 = f2bf(va.y - bf2f(h1)),
                             g2 = f2bf(vb.x - bf2f(h2)), g3 = f2bf(vb.y - bf2f(h3));
        uint2 hi2, lo2;
        hi2.x = (unsigned)h0 | ((unsigned)h1 << 16);
        hi2.y = (unsigned)h2 | ((unsigned)h3 << 16);
        lo2.x = (unsigned)g0 | ((unsigned)g1 << 16);
        lo2.y = (unsigned)g2 | ((unsigned)g3 << 16);
        const int off = row * 1024 + ((col * 2) ^ ((row & 7) << 4));
        *(uint2*)(lds + 65536 + off) = hi2;
        *(uint2*)(lds + 98304 + off) = lo2;
    }
    // ---- stage cb chunk 0 (linear 32KB copy) ----
    #pragma unroll
    for (int i = 0; i < 4; ++i) {
        const int u = i * 512 + tid;
        __builtin_amdgcn_global_load_lds(
            (const __attribute__((address_space(1))) void*)(img + (size_t)u * 16),
            (__attribute__((address_space(3))) void*)
                (lds + (size_t)(i * 512 + (tid & ~63)) * 16),
            16, 0, 0);
    }
    __syncthreads();

    f32x4 acc00 = {0.f,0.f,0.f,0.f}, acc01 = {0.f,0.f,0.f,0.f};
    f32x4 acc10 = {0.f,0.f,0.f,0.f}, acc11 = {0.f,0.f,0.f,0.f};

    const int swz = (l15 & 7) << 4;           // same for A rows and B codes
    const char* zh0 = lds + 65536 + l15 * 1024;
    const char* zl0 = lds + 98304 + l15 * 1024;
    const int code0  = wn * 32 + l15;
    const int cboff0 = code0 * 128;

    int buf = 0;
    for (int c = 0; c < NCHUNK; ++c) {
        if (c < NCHUNK - 1) {                 // depth-1 prefetch into buf^1
            const char* g = img + (size_t)(c + 1) * CHB;
            #pragma unroll
            for (int i = 0; i < 4; ++i) {
                const int u = i * 512 + tid;
                __builtin_amdgcn_global_load_lds(
                    (const __attribute__((address_space(1))) void*)(g + (size_t)u * 16),
                    (__attribute__((address_space(3))) void*)
                        (lds + (buf ^ 1) * 32768 + (size_t)(i * 512 + (tid & ~63)) * 16),
                    16, 0, 0);
            }
        }
        const int kzB = (c * 128 + kh * 64 + kg16) ^ swz;  // z-row byte offset
        const int kcB = (kh * 64 + kg16) ^ swz;            // cb-row byte offset
        const char* cbb = lds + buf * 32768;
        const bf16x8 a0h = *(const bf16x8*)(zh0 + kzB);
        const bf16x8 a0l = *(const bf16x8*)(zl0 + kzB);
        const bf16x8 a1h = *(const bf16x8*)(zh0 + 16384 + kzB);   // row +16
        const bf16x8 a1l = *(const bf16x8*)(zl0 + 16384 + kzB);
        const bf16x8 b0h = *(const bf16x8*)(cbb + cboff0 + kcB);
        const bf16x8 b0l = *(const bf16x8*)(cbb + 16384 + cboff0 + kcB);
        const bf16x8 b1h = *(const bf16x8*)(cbb + cboff0 + 2048 + kcB); // code +16
        const bf16x8 b1l = *(const bf16x8*)(cbb + 16384 + cboff0 + 2048 + kcB);
        acc00 = MFMA16(a0h, b0h, acc00, 0, 0, 0);
        acc01 = MFMA16(a0h, b1h, acc01, 0, 0, 0);
        acc10 = MFMA16(a1h, b0h, acc10, 0, 0, 0);
        acc11 = MFMA16(a1h, b1h, acc11, 0, 0, 0);
        acc00 = MFMA16(a0h, b0l, acc00, 0, 0, 0);
        acc01 = MFMA16(a0h, b1l, acc01, 0, 0, 0);
        acc10 = MFMA16(a1h, b0l, acc10, 0, 0, 0);
        acc11 = MFMA16(a1h, b1l, acc11, 0, 0, 0);
        acc00 = MFMA16(a0l, b0h, acc00, 0, 0, 0);
        acc01 = MFMA16(a0l, b1h, acc01, 0, 0, 0);
        acc10 = MFMA16(a1l, b0h, acc10, 0, 0, 0);
        acc11 = MFMA16(a1l, b1h, acc11, 0, 0, 0);
        __syncthreads();                      // drains prefetch + read fences
        buf ^= 1;
    }

    // ---- epilogue scratch (cb buffers + z region now dead) ----
    float* ef  = (float*)lds;                 // [16 slots][256] = 16KB
    float* tv1 = (float*)(lds + 65536);       // [4][32]
    int*   ti1 = (int*)  (lds + 66048);
    float* tv2 = (float*)(lds + 66560);
    int*   ti2 = (int*)  (lds + 67072);
    int*   i1a = (int*)  (lds + 67584);       // [32]
    int*   i2a = (int*)  (lds + 67712);
    int*   flg = (int*)  (lds + 67840);
    int*   kbf = (int*)  (lds + 67968);
    float* rsum= (float*)(lds + 68096);       // [8]

    // K-half merge: kh=1 exports partial accs (conflict-free scalar layout)
    if (kh == 1) {
        const int base = wn * 64 + lane;
        #pragma unroll
        for (int j = 0; j < 4; ++j) {
            ef[(0 + j) * 256 + base]  = acc00[j];
            ef[(4 + j) * 256 + base]  = acc01[j];
            ef[(8 + j) * 256 + base]  = acc10[j];
            ef[(12 + j) * 256 + base] = acc11[j];
        }
    }
    __syncthreads();
    if (kh == 0) {
        const int base = wn * 64 + lane;
        #pragma unroll
        for (int j = 0; j < 4; ++j) {
            acc00[j] += ef[(0 + j) * 256 + base];
            acc01[j] += ef[(4 + j) * 256 + base];
            acc10[j] += ef[(8 + j) * 256 + base];
            acc11[j] += ef[(12 + j) * 256 + base];
        }
        const float cn0 = cnorm[code0];
        const float cn1 = cnorm[code0 + 16];
        // per-row top-2 over this wave's 32 codes; 16-lane shuffle reduce
        #pragma unroll
        for (int rf = 0; rf < 2; ++rf) {
            #pragma unroll
            for (int j = 0; j < 4; ++j) {
                const float va = cn0 - 2.f * (rf ? acc10[j] : acc00[j]);
                const float vb = cn1 - 2.f * (rf ? acc11[j] : acc01[j]);
                float v1, v2; int i1, i2;
                if (vb < va) { v1 = vb; i1 = code0 + 16; v2 = va; i2 = code0; }
                else         { v1 = va; i1 = code0;      v2 = vb; i2 = code0 + 16; }
                #pragma unroll
                for (int m = 1; m < 16; m <<= 1) {
                    const float o1 = __shfl_xor(v1, m, 64); const int oi1 = __shfl_xor(i1, m, 64);
                    const float o2 = __shfl_xor(v2, m, 64); const int oi2 = __shfl_xor(i2, m, 64);
                    if (lexlt(o1, oi1, v1, i1)) {
                        if (lexlt(v1, i1, o2, oi2)) { v2 = v1; i2 = i1; }
                        else                        { v2 = o2; i2 = oi2; }
                        v1 = o1; i1 = oi1;
                    } else if (lexlt(o1, oi1, v2, i2)) { v2 = o1; i2 = oi1; }
                }
                if (l15 == 0) {
                    const int mrow = rf * 16 + (lane >> 4) * 4 + j;
                    tv1[wn * 32 + mrow] = v1; ti1[wn * 32 + mrow] = i1;
                    tv2[wn * 32 + mrow] = v2; ti2[wn * 32 + mrow] = i2;
                }
            }
        }
    }
    __syncthreads();

    // merge 4 code-groups -> global top2 per row; flag ambiguous rows
    if (tid < 32) {
        float v1 = tv1[tid]; int i1 = ti1[tid];
        float v2 = tv2[tid]; int i2 = ti2[tid];
        #pragma unroll
        for (int w = 1; w < 4; ++w) {
            const float o1 = tv1[w * 32 + tid], o2 = tv2[w * 32 + tid];
            const int  oi1 = ti1[w * 32 + tid], oi2 = ti2[w * 32 + tid];
            if (lexlt(o1, oi1, v1, i1)) {
                if (lexlt(v1, i1, o2, oi2)) { v2 = v1; i2 = i1; }
                else                        { v2 = o2; i2 = oi2; }
                v1 = o1; i1 = oi1;
            } else if (lexlt(o1, oi1, v2, i2)) { v2 = o1; i2 = oi1; }
        }
        i1a[tid] = i1; i2a[tid] = i2;
        flg[tid] = (v2 - v1 < TAU) ? 1 : 0;
        kbf[tid] = i1;
    }
    __syncthreads();

    // tau-gated exact f32 refinement (rare; uniform branch per row)
    for (int row = 0; row < 32; ++row) {
        if (!flg[row]) continue;
        const int cand = (tid < 256) ? i1a[row] : i2a[row];
        const float* zr = (row < 16) ? z + (size_t)(r0 + row) * D
                                     : zp + (size_t)(r0 + row - 16) * D;
        const float* cr = cb + (size_t)cand * D;
        const int t = tid & 255;
        float dot = 0.f;
        const int col = t * 2;
        if (col < D) {
            const float2 a = *(const float2*)(zr + col);
            const float2 b = *(const float2*)(cr + col);
            dot = fmaf(a.y, b.y, a.x * b.x);
        }
        #pragma unroll
        for (int m = 1; m < 64; m <<= 1) dot += __shfl_xor(dot, m, 64);
        if (lane == 0) rsum[wu] = dot;
        __syncthreads();
        if (tid == 0) {
            const int ia = i1a[row], ib = i2a[row];
            const float da = cnorm[ia] - 2.f * (rsum[0] + rsum[1] + rsum[2] + rsum[3]);
            const float db = cnorm[ib] - 2.f * (rsum[4] + rsum[5] + rsum[6] + rsum[7]);
            if (lexlt(db, ib, da, ia)) kbf[row] = ib;
        }
        __syncthreads();
    }

    // fused gather: 16 output rows x 32 lanes
    const int grow = tid >> 5;                // 0..15
    const int l31  = tid & 31;
    const int kz   = kbf[grow];
    const int kzp2 = kbf[16 + grow];
    const int pp   = pos[r0 + grow];
    const float* ra = cb + (size_t)kz * D;
    const float* rb = cb + (size_t)kzp2 * D;
    const float* rp = ph + (size_t)pp * D;
    float* ro = out + (size_t)(r0 + grow) * D;
    #pragma unroll
    for (int it = 0; it < 8; ++it) {
        const int col = l31 * 2 + it * 64;
        if (col < D) {
            const float2 a = *(const float2*)(ra + col);
            const float2 b = *(const float2*)(rb + col);
            const float2 p = *(const float2*)(rp + col);
            float2 o; o.x = a.x + b.x + p.x; o.y = a.y + b.y + p.y;
            *(float2*)(ro + col) = o;
        }
    }
}

extern "C" void kernel_launch(void* const* d_in, const int* in_sizes, int n_in,
                              void* d_out, int out_size, void* d_ws, size_t ws_size,
                              hipStream_t stream) {
    const float* z  = (const float*)d_in[0];
    const float* zp = (const float*)d_in[1];
    const float* cb = (const float*)d_in[2];
    const float* ph = (const float*)d_in[3];
    const int*   pos = (const int*)d_in[4];
    float* out = (float*)d_out;

    float* cnorm = (float*)d_ws;          // 128 floats
    char*  img   = (char*)d_ws + 512;     // 256KB pre-swizzled hi/lo image

    prep_kernel<<<K_CODES, 64, 0, stream>>>(cb, cnorm, img);
    main_kernel<<<BHALF / 16, 512, 0, stream>>>(z, zp, cb, ph, pos, cnorm, img, out);
}